// Round 4
// baseline (53.281 us; speedup 1.0000x reference)
//
#include <hip/hip_runtime.h>

#define B_ 8
#define C_ 256
#define S_ 2048
#define T_ (B_*S_)      // 16384 tokens

typedef short s8v __attribute__((ext_vector_type(8)));
typedef short s4v __attribute__((ext_vector_type(4)));
typedef float f4v __attribute__((ext_vector_type(4)));

__device__ inline short f2b(float f){            // fp32 -> bf16 RNE
  unsigned u = __builtin_bit_cast(unsigned, f);
  unsigned r = (u + 0x7FFFu + ((u >> 16) & 1u)) >> 16;
  return (short)r;
}
__device__ inline float b2f(short s){
  unsigned u = ((unsigned)(unsigned short)s) << 16;
  return __builtin_bit_cast(float, u);
}

// K1: weight (R,C,M) fp32 -> wT (R,M,C) bf16 (so B-fragments are k-contiguous)
__global__ __launch_bounds__(256) void k_tw(const float* __restrict__ wgt, short* __restrict__ wT){
  int bid = blockIdx.x;
  int r  = bid >> 4;
  int ct = (bid >> 2) & 3;
  int mt = bid & 3;
  __shared__ float tile[64][65];
  int tid = threadIdx.x;
  const float* wb = wgt + r*(C_*256);
  #pragma unroll
  for (int it = 0; it < 4; ++it){
    int row = it*16 + (tid >> 4);       // c-local
    int m4  = tid & 15;
    float4 v = *(const float4*)(wb + (ct*64 + row)*256 + mt*64 + m4*4);
    tile[row][m4*4+0] = v.x; tile[row][m4*4+1] = v.y;
    tile[row][m4*4+2] = v.z; tile[row][m4*4+3] = v.w;
  }
  __syncthreads();
  #pragma unroll
  for (int it = 0; it < 4; ++it){
    int mrow = it*16 + (tid >> 4);      // m-local
    int c4   = tid & 15;
    s4v o;
    o[0] = f2b(tile[c4*4+0][mrow]); o[1] = f2b(tile[c4*4+1][mrow]);
    o[2] = f2b(tile[c4*4+2][mrow]); o[3] = f2b(tile[c4*4+3][mrow]);
    *(s4v*)(wT + r*65536 + (mt*64 + mrow)*256 + ct*64 + c4*4) = o;
  }
}

// K2: fully fused. Block = (64-token s-tile, n-half of 128). Grid 512 (2 blocks/CU).
// Phases: counting-sort 64 tokens by expert -> stage x-tile transposed(bf16,swizzled)
// into LDS by sorted slot -> per mi(16 rows): MFMA only experts present in that row
// group (rate-gated), B-fragments global->VGPR from L2-resident wT -> merge per-row
// by expert match (bias fused) -> masked epilogue: outx via LDS transpose stage,
// outm computed directly; coalesced (B,C,S) writes. idx passthrough fused.
__global__ __launch_bounds__(256,2) void k_fused(const float* __restrict__ x,
    const short* __restrict__ wT, const float* __restrict__ bias,
    const int* __restrict__ idx, const int* __restrict__ rate,
    float* __restrict__ outx, float* __restrict__ outm, float* __restrict__ idx_out)
{
  int bid  = blockIdx.x;
  int half = bid & 1;
  int tile = bid >> 1;
  int b  = tile >> 5;
  int s0 = (tile & 31) << 6;
  int nb = half << 7;                 // n-half base: 0 or 128

  __shared__ short A[64*256];         // 32 KB bf16 [slot q][c], XOR-swizzled
  __shared__ float outS[4][32][68];   // 34.8 KB per-wave fp32 out-stage [mlocal][s]
  __shared__ int eOrd[64];            // slot q   -> s-local
  __shared__ int rankOf[64];          // s-local  -> slot q
  __shared__ int eSlot[64];           // slot q   -> expert
  __shared__ int rateO64[64];         // s-local  -> rate>>5
  __shared__ int eRange[4];           // per mi: elo | ehi<<8
  __shared__ int lcount[8], lbase[8], rateE[8];

  int tid  = threadIdx.x;
  int lane = tid & 63, wv = tid >> 6;
  int l15  = lane & 15, lq = lane >> 4;

  // ---- block-local counting sort of 64 tokens by expert ----
  if (tid < 8){ lcount[tid] = 0; rateE[tid] = rate[tid]; }
  __syncthreads();
  int myE = 0, myRank = 0;
  if (tid < 64){
    myE = idx[b*S_ + s0 + tid] & 7;
    myRank = atomicAdd(&lcount[myE], 1);
  }
  __syncthreads();
  if (tid == 0){
    int a0 = 0;
    #pragma unroll
    for (int e = 0; e < 8; ++e){ lbase[e] = a0; a0 += lcount[e]; }
  }
  __syncthreads();
  if (tid < 64){
    int q = lbase[myE] + myRank;
    rankOf[tid] = q;
    eOrd[q]     = tid;
    eSlot[q]    = myE;
    rateO64[tid] = rateE[myE] >> 5;
    if (half == 0) idx_out[b*S_ + s0 + tid] = (float)myE;
  }
  __syncthreads();
  if (tid < 4) eRange[tid] = eSlot[tid*16] | (eSlot[tid*16 + 15] << 8);

  // ---- stage A: x (c-major) -> A[slot][c] bf16, swizzled ----
  char* AB = (char*)A;
  {
    const float* xb = x + b*(C_*S_) + s0;
    int sl4 = (tid & 15) * 4;
    int c0  = tid >> 4;
    int q0 = rankOf[sl4+0], q1 = rankOf[sl4+1], q2 = rankOf[sl4+2], q3 = rankOf[sl4+3];
    #pragma unroll
    for (int it = 0; it < 16; ++it){
      int c = it*16 + c0;
      float4 v = *(const float4*)(xb + c*S_ + sl4);
      *(short*)(AB + ((q0*512 + c*2) ^ ((q0 & 7) << 4))) = f2b(v.x);
      *(short*)(AB + ((q1*512 + c*2) ^ ((q1 & 7) << 4))) = f2b(v.y);
      *(short*)(AB + ((q2*512 + c*2) ^ ((q2 & 7) << 4))) = f2b(v.z);
      *(short*)(AB + ((q3*512 + c*2) ^ ((q3 & 7) << 4))) = f2b(v.w);
    }
  }
  __syncthreads();

  int m0 = nb + wv*32;                // this wave's 32-wide n-range

  // pack per-lane row experts / rates (rows q = mi*16 + lq*4 + r)
  int epk[4], rpk[4];
  #pragma unroll
  for (int mi = 0; mi < 4; ++mi){
    int qb = mi*16 + lq*4;
    int e0 = eSlot[qb+0], e1 = eSlot[qb+1], e2 = eSlot[qb+2], e3 = eSlot[qb+3];
    epk[mi] = e0 | (e1 << 8) | (e2 << 16) | (e3 << 24);
    rpk[mi] = (rateE[e0] >> 5) | ((rateE[e1] >> 5) << 8)
            | ((rateE[e2] >> 5) << 16) | ((rateE[e3] >> 5) << 24);
  }

  f4v acc[4][2];
  #pragma unroll
  for (int mi = 0; mi < 4; ++mi)
    #pragma unroll
    for (int ni = 0; ni < 2; ++ni)
      acc[mi][ni] = (f4v){0.f, 0.f, 0.f, 0.f};

  #pragma unroll
  for (int mi = 0; mi < 4; ++mi){
    int row = mi*16 + l15;
    s8v a[8];
    #pragma unroll
    for (int k = 0; k < 8; ++k)
      a[k] = *(const s8v*)(AB + ((row*512 + k*64 + lq*16) ^ ((row & 7) << 4)));
    int rg = eRange[mi], elo = rg & 255, ehi = rg >> 8;
    for (int e = elo; e <= ehi; ++e){
      if (rateE[e] <= m0) continue;                  // whole wave n-range masked out
      const short* wTe = wT + e*65536;
      #pragma unroll
      for (int ni = 0; ni < 2; ++ni){
        int m = m0 + ni*16 + l15;
        const short* bp = wTe + m*256 + lq*8;
        s8v bv[8];
        #pragma unroll
        for (int k = 0; k < 8; ++k) bv[k] = *(const s8v*)(bp + k*32);
        f4v t = (f4v){0.f, 0.f, 0.f, 0.f};
        #pragma unroll
        for (int k = 0; k < 8; ++k)
          t = __builtin_amdgcn_mfma_f32_16x16x32_bf16(a[k], bv[k], t, 0, 0, 0);
        float bs = bias[e*256 + m];
        #pragma unroll
        for (int r = 0; r < 4; ++r){
          bool hit = (((epk[mi] >> (r*8)) & 255) == e);   // exactly one e matches per row
          acc[mi][ni][r] = hit ? (t[r] + bs) : acc[mi][ni][r];
        }
      }
    }
  }

  // ---- epilogue: residual + mask, stage per-wave to LDS, coalesced write ----
  int mk = m0 >> 5;                    // rate granularity is 32: keep iff mk < rate32[row]
  float* oS = &outS[wv][0][0];
  #pragma unroll
  for (int mi = 0; mi < 4; ++mi){
    #pragma unroll
    for (int ni = 0; ni < 2; ++ni){
      int m = m0 + ni*16 + l15;
      #pragma unroll
      for (int r = 0; r < 4; ++r){
        int q = mi*16 + lq*4 + r;
        float xres = b2f(*(const short*)(AB + ((q*512 + m*2) ^ ((q & 7) << 4))));
        int  rt32 = (rpk[mi] >> (r*8)) & 255;
        float val = (mk < rt32) ? (acc[mi][ni][r] + xres) : 0.0f;
        oS[(ni*16 + l15)*68 + eOrd[q]] = val;       // unpermute to s-local
      }
    }
  }
  __syncthreads();
  {
    int sv = l15 * 4;                  // 4 s-positions per lane
    float4 omv;
    omv.x = (mk < rateO64[sv+0]) ? 1.0f : 0.0f;
    omv.y = (mk < rateO64[sv+1]) ? 1.0f : 0.0f;
    omv.z = (mk < rateO64[sv+2]) ? 1.0f : 0.0f;
    omv.w = (mk < rateO64[sv+3]) ? 1.0f : 0.0f;
    float* ob = outx + b*(C_*S_) + s0;
    float* om = outm + b*(C_*S_) + s0;
    #pragma unroll
    for (int it = 0; it < 8; ++it){
      int mr = it*4 + lq;
      int m  = m0 + mr;
      float4 v = *(const float4*)&outS[wv][mr][sv];
      *(float4*)(ob + m*S_ + sv) = v;
      *(float4*)(om + m*S_ + sv) = omv;
    }
  }
}

extern "C" void kernel_launch(void* const* d_in, const int* in_sizes, int n_in,
                              void* d_out, int out_size, void* d_ws, size_t ws_size,
                              hipStream_t stream){
  const float* x    = (const float*)d_in[0];
  const int*   idx  = (const int*)d_in[1];     // int32 (harness: integer -> const int*)
  const float* wgt  = (const float*)d_in[2];
  const float* bias = (const float*)d_in[3];
  const int*   rate = (const int*)d_in[4];

  short* wT = (short*)d_ws;                    // 1 MB bf16 (R,M,C)

  float* outx    = (float*)d_out;
  float* outm    = outx + (B_*C_*S_);
  float* idx_out = outx + 2*(B_*C_*S_);

  k_tw   <<<128, 256, 0, stream>>>(wgt, wT);
  k_fused<<<512, 256, 0, stream>>>(x, wT, bias, idx, rate, outx, outm, idx_out);
}